// Round 2
// baseline (611.116 us; speedup 1.0000x reference)
//
#include <hip/hip_runtime.h>
#include <stdint.h>

#define NN 128
#define BB 4096
#define HH 32

// Pre-pass: bit-pack A transposed into column masks.
// bitsW layout (as u64): index (b*128 + col)*2 + h, h=0 -> d 0..63, h=1 -> d 64..127.
// Thread (b, n4, h) owns columns 4*n4..4*n4+3 for d-range h*64..h*64+63.
// Wave reads 2 contiguous 512B segments per iteration (1 KiB/instr, fully coalesced).
__global__ __launch_bounds__(256) void pack_bits(const float* __restrict__ A,
                                                 unsigned long long* __restrict__ bitsW) {
    int t = blockIdx.x * 256 + threadIdx.x;   // BB*64 threads total
    int n4 = t & 31;
    int h  = (t >> 5) & 1;
    int b  = t >> 6;
    const float4* Ap = (const float4*)(A + (size_t)b * NN * NN + (size_t)h * 64 * NN) + n4;
    unsigned long long m0 = 0, m1 = 0, m2 = 0, m3 = 0;
#pragma unroll 8
    for (int d = 0; d < 64; ++d) {
        float4 v = Ap[(size_t)d * (NN / 4)];
        unsigned long long bit = 1ull << d;
        if (v.x != 0.f) m0 |= bit;
        if (v.y != 0.f) m1 |= bit;
        if (v.z != 0.f) m2 |= bit;
        if (v.w != 0.f) m3 |= bit;
    }
    unsigned long long* dst = bitsW + ((size_t)b * NN + n4 * 4) * 2 + h;
    dst[0] = m0; dst[2] = m1; dst[4] = m2; dst[6] = m3;
}

// Two waves (128 threads) per batch element. Both waves hold a replicated copy of the
// 128-entry outputs state (out0: d=lane, out1: d=lane+64) and compute ballots/epilogue
// redundantly (bitwise identical). The sparse W1-row gather is split 4 ways by
// quarter = tid>>5; partials merge via shfl_xor(32) within-wave + 64B LDS cross-wave.
__global__ __launch_bounds__(128) void cond_mlp(
    const float* __restrict__ x, const float* __restrict__ u,
    const float* __restrict__ W1, const float* __restrict__ b1,
    const float* __restrict__ W2, const float* __restrict__ b2,
    const int* __restrict__ order, const int* __restrict__ do_idxs,
    const ulonglong2* __restrict__ bitsT, float* __restrict__ out)
{
    const int b = blockIdx.x;
    const int tid = threadIdx.x;          // 0..127
    const int lane = tid & 63;
    const int wv = tid >> 6;              // wave id 0/1
    const int j = tid & 31;               // hidden index
    const int quarter = (tid >> 5) & 3;   // k-stream 0..3

    __shared__ float2 ent[132];           // compacted (value, d-as-bits) list
    __shared__ float part[2][32];         // cross-wave partial sums

    const float ub = u[b];
    const int dob = do_idxs[b];
    float out0 = (dob == lane) ? ub : 0.f;
    float out1 = (dob == lane + 64) ? ub : 0.f;

    const int* ord = order + b * NN;
    const ulonglong2* bb = bitsT + (size_t)b * NN;

    int node = ord[0];
    ulonglong2 bits = bb[node];

    for (int t = 0; t < NN; ++t) {
        // ---- prefetch next step's uniform data ----
        const int node_n = (t < NN - 1) ? ord[t + 1] : 0;
        const ulonglong2 bits_n = bb[node_n];

        const float* Wn = W1 + (size_t)node * (NN + 1) * HH;
        const float w2v = W2[node * HH + j];
        const float b1v = b1[node * HH + j];
        const float xv  = x[b * NN + node];
        const float b2v = b2[node];

        // ---- wave-uniform sparse compaction (identical in both waves) ----
        unsigned long long bal0 = __ballot(out0 != 0.f) & bits.x;
        unsigned long long bal1 = __ballot(out1 != 0.f) & bits.y;
        const int c0 = __popcll(bal0);
        const int cnt = c0 + __popcll(bal1);
        const int cnt4 = (cnt + 3) & ~3;
        if (wv == 0) {
            const unsigned long long below = (1ull << lane) - 1;
            if (bal0 & (1ull << lane)) {
                int p = __popcll(bal0 & below);
                ent[p] = make_float2(out0, __int_as_float(lane));
            }
            if (bal1 & (1ull << lane)) {
                int p = c0 + __popcll(bal1 & below);
                ent[p] = make_float2(out1, __int_as_float(lane + 64));
            }
            if (lane < cnt4 - cnt) ent[cnt + lane] = make_float2(0.f, __int_as_float(0));
        }
        __syncthreads();   // barrier A: ent visible to both waves

        // ---- sparse gather, 4-way split ----
        float acc = 0.f;
        for (int k = quarter; k < cnt4; k += 4) {
            float2 e = ent[k];
            acc += e.x * Wn[__float_as_int(e.y) * HH + j];
        }
        acc += __shfl_xor(acc, 32);        // merge quarter pair within wave
        if (lane < 32) part[wv][j] = acc;
        __syncthreads();   // barrier B: partials visible; also protects ent reuse

        float acc2 = acc + part[1 - wv][j];
        acc2 += xv * Wn[NN * HH + j];      // x input row (row 128)
        acc2 += b1v;
        const float hv = (acc2 > 0.f) ? acc2 : 0.01f * acc2;   // leaky_relu

        float p = hv * w2v;                // H -> 1 reduction (within 32-lane halves)
        p += __shfl_xor(p, 16);
        p += __shfl_xor(p, 8);
        p += __shfl_xor(p, 4);
        p += __shfl_xor(p, 2);
        p += __shfl_xor(p, 1);
        const float outv = p + b2v;

        // ---- replicated state update (skip if do-intervention node) ----
        if (dob != node) {
            if (lane == (node & 63)) {
                if (node < 64) out0 = outv; else out1 = outv;
            }
        }
        node = node_n;
        bits = bits_n;
    }

    if (wv == 0) {
        out[b * NN + lane] = out0;
        out[b * NN + 64 + lane] = out1;
    }
}

extern "C" void kernel_launch(void* const* d_in, const int* in_sizes, int n_in,
                              void* d_out, int out_size, void* d_ws, size_t ws_size,
                              hipStream_t stream) {
    const float* x   = (const float*)d_in[0];
    const float* A   = (const float*)d_in[1];
    const float* u   = (const float*)d_in[2];
    const float* W1  = (const float*)d_in[3];
    const float* b1  = (const float*)d_in[4];
    const float* W2  = (const float*)d_in[5];
    const float* b2  = (const float*)d_in[6];
    const int* order = (const int*)d_in[7];
    const int* dox   = (const int*)d_in[8];

    unsigned long long* bitsW = (unsigned long long*)d_ws;  // 4096*128*16 B = 8 MB

    pack_bits<<<(BB * 64) / 256, 256, 0, stream>>>(A, bitsW);
    cond_mlp<<<BB, 128, 0, stream>>>(x, u, W1, b1, W2, b2, order, dox,
                                     (const ulonglong2*)bitsW, (float*)d_out);
}